// Round 2
// baseline (230.195 us; speedup 1.0000x reference)
//
#include <hip/hip_runtime.h>
#include <cstdint>
#include <cmath>

#define NROWS 8192
#define KDIM  512            // elements; also bytes/row in fp8

typedef int    i32x4  __attribute__((ext_vector_type(4)));
typedef int    i32x8  __attribute__((ext_vector_type(8)));
typedef float  f32x16 __attribute__((ext_vector_type(16)));
typedef unsigned char u8;

#define AS1(p) ((const __attribute__((address_space(1))) void*)(p))
#define AS3(p) ((__attribute__((address_space(3))) void*)(p))

// contributing gemm blocks: pos upper-tri 1056 + neg 2048
#define TOTAL_BLOCKS 3104u

// --- Kernel 1: row L2-normalize fp32 -> fp8 e4m3 (OCP, HW cvt), one wave/row.
// zi rows [0,8192), zj rows [8192,16384). Also zeroes the 128 accumulator slots
// and the last-block counter (finalize fused into the gemm kernel).
__global__ __launch_bounds__(256) void nrm_kernel(const float* __restrict__ zi,
                                                  const float* __restrict__ zj,
                                                  u8* __restrict__ out,
                                                  double* __restrict__ acc,
                                                  unsigned* __restrict__ cnt) {
    if (blockIdx.x == 0) {
        if (threadIdx.x < 128) acc[threadIdx.x] = 0.0;
        if (threadIdx.x == 128) *cnt = 0u;
    }
    const int wave = threadIdx.x >> 6;
    const int lane = threadIdx.x & 63;
    const int row  = blockIdx.x * 4 + wave;            // 0..16383
    const float* src = (row < NROWS) ? zi + (size_t)row * KDIM
                                     : zj + (size_t)(row - NROWS) * KDIM;
    float4 a = ((const float4*)src)[lane];
    float4 b = ((const float4*)src)[lane + 64];
    float ss = a.x*a.x + a.y*a.y + a.z*a.z + a.w*a.w
             + b.x*b.x + b.y*b.y + b.z*b.z + b.w*b.w;
    #pragma unroll
    for (int off = 32; off >= 1; off >>= 1) ss += __shfl_xor(ss, off, 64);
    const float inv = 1.0f / fmaxf(sqrtf(ss), 1e-12f);
    int p0 = 0, p1 = 0;
    p0 = __builtin_amdgcn_cvt_pk_fp8_f32(a.x * inv, a.y * inv, p0, false);
    p0 = __builtin_amdgcn_cvt_pk_fp8_f32(a.z * inv, a.w * inv, p0, true);
    p1 = __builtin_amdgcn_cvt_pk_fp8_f32(b.x * inv, b.y * inv, p1, false);
    p1 = __builtin_amdgcn_cvt_pk_fp8_f32(b.z * inv, b.w * inv, p1, true);
    int* dst = (int*)(out + (size_t)row * KDIM);
    dst[lane]      = p0;
    dst[lane + 64] = p1;
}

// --- Kernel 2: fused MX-fp8 A*B^T -> exp(10*dot) -> global sum -> (last block) loss.
// R13: compiler-cooperative 2-phase pipeline (T3 minimum recipe).
// R12 post-mortem: sched_barrier(0) pinning (m141 trap) + runtime-indexed double
// buffer lA[cur] forced the compiler to insert its own vmcnt(0) before the
// fragment ds_reads (can't prove ds_read(lA[cur]) doesn't alias the
// global_load_lds writes to lA[cur^1]) -> drained the just-issued loads every
// K-step -> 2x regression. Fix here:
//   * DISTINCT named __shared__ arrays lA0/lA1, lB0/lB1 + fully unrolled
//     even/odd loop -> buffer choice is compile-time -> alias analysis proves
//     reads and staged writes disjoint -> no forced drain before ds_reads.
//   * Stage-early / drain-late: issue tile t+1's 6 global_load_lds at the TOP
//     of the iteration, then ds_read+8 MFMAs on tile t (~300+ cyc), then plain
//     __syncthreads() whose built-in vmcnt(0) waits on loads that already had
//     the whole compute phase to land. R11 paid this latency with zero overlap.
//   * No inline asm, no sched_barrier, no setprio (T5 is null on 2-phase).
// LDS XOR-swizzle unchanged (verified R2-R12, absmax 0): region = 32 rows x
// 64 B; chunk (r,b) at p = r*4 + (b ^ ((r>>1)&3)); staging inverse
// b = (lane&3)^((lane>>3)&3). Triangle skip unchanged. Fused finalize
// (verified R12, absmax 0): last contributing block reduces the 128 slots.
__global__ __launch_bounds__(256, 2) void gemm_exp_reduce(const u8* __restrict__ A,
                                                          const u8* __restrict__ B,
                                                          double* __restrict__ acc,
                                                          unsigned* __restrict__ cnt,
                                                          float* __restrict__ out) {
    const int bx = blockIdx.x, by = blockIdx.y;
    const bool pos = (bx < 64);
    if (pos && bx < 2 * by) return;   // strict lower-tri pos block: mirror elsewhere

    __shared__ u8 lA0[256 * 64];     // ping buffer, 16 KB (8 regions of 32r x 64B)
    __shared__ u8 lA1[256 * 64];     // pong buffer
    __shared__ u8 lB0[128 * 64];     // ping, 8 KB (4 regions)
    __shared__ u8 lB1[128 * 64];     // pong
    __shared__ float red[4];
    __shared__ double dred[2];
    __shared__ unsigned amLast;

    const int tid  = threadIdx.x;
    const int lane = tid & 63;
    const int wave = tid >> 6;
    const int m0   = by * 256;
    const int n0   = bx * 128;
    const int wm   = (wave >> 1) * 128;
    const int wn   = (wave & 1) * 64;

    f32x16 accf[4][2];
    #pragma unroll
    for (int i = 0; i < 4; ++i)
        #pragma unroll
        for (int j = 0; j < 2; ++j)
            #pragma unroll
            for (int r = 0; r < 16; ++r)
                accf[i][j][r] = 0.f;

    // staging (layout verified R2-R12): 16-row chunks of 1024 B per k-step.
    // A: wave does chunks wave*4..+3; B: wave*2..+1.
    // lane: global row = chunk*16 + (lane>>2), 16B-col bsw = (lane&3)^((lane>>3)&3).
    const int bsw = (lane & 3) ^ ((lane >> 3) & 3);
    const u8* gA0 = A + (size_t)(m0 + wave * 64 + (lane >> 2)) * KDIM + bsw * 16;
    const u8* gB0 = B + (size_t)(n0 + wave * 32 + (lane >> 2)) * KDIM + bsw * 16;
    const int ldsA = wave * 4096 + lane * 16;
    const int ldsB = wave * 2048 + lane * 16;

    // stage one BK=64 k-slice (6 x global_load_lds dwordx4 per thread)
    auto stage = [&](int t, u8 (&dA)[256 * 64], u8 (&dB)[128 * 64]) {
        const size_t kb = (size_t)t * 64;
        #pragma unroll
        for (int c = 0; c < 4; ++c)
            __builtin_amdgcn_global_load_lds(AS1(gA0 + kb + (size_t)c * 16 * KDIM),
                                             AS3(&dA[ldsA + c * 1024]), 16, 0, 0);
        #pragma unroll
        for (int c = 0; c < 2; ++c)
            __builtin_amdgcn_global_load_lds(AS1(gB0 + kb + (size_t)c * 16 * KDIM),
                                             AS3(&dB[ldsB + c * 1024]), 16, 0, 0);
    };

    // fragment read: lane row r=lane&31, k-half-of-64 q=lane>>5 (chunks 2q,2q+1);
    // swizzled position p = r*4 + ((2q) ^ ((r>>1)&3)); partner chunk at ^16.
    const int r_  = lane & 31;
    const int q_  = lane >> 5;
    const int p16 = (r_ * 4 + ((2 * q_) ^ ((r_ >> 1) & 3))) * 16;
    const int aT0 = (wave >> 1) * 4;   // A regions aT0..aT0+3 (128 rows)
    const int bT0 = (wave & 1) * 2;    // B regions bT0..bT0+1 (64 rows)

    // ds_read fragments + 8 MFMAs for one staged BK=64 tile
    auto compute = [&](const u8 (&sA)[256 * 64], const u8 (&sB)[128 * 64]) {
        i32x8 af[4], bfr[2];
        #pragma unroll
        for (int mi = 0; mi < 4; ++mi) {
            const int off = (aT0 + mi) * 2048 + p16;
            *(i32x4*)&af[mi]       = *(const i32x4*)&sA[off];
            *((i32x4*)&af[mi] + 1) = *(const i32x4*)&sA[off ^ 16];
        }
        #pragma unroll
        for (int ni = 0; ni < 2; ++ni) {
            const int off = (bT0 + ni) * 2048 + p16;
            *(i32x4*)&bfr[ni]       = *(const i32x4*)&sB[off];
            *((i32x4*)&bfr[ni] + 1) = *(const i32x4*)&sB[off ^ 16];
        }
        #pragma unroll
        for (int mi = 0; mi < 4; ++mi)
            #pragma unroll
            for (int ni = 0; ni < 2; ++ni)
                accf[mi][ni] = __builtin_amdgcn_mfma_scale_f32_32x32x64_f8f6f4(
                    af[mi], bfr[ni], accf[mi][ni],
                    0, 0,                 // cbsz=fp8(e4m3), blgp=fp8(e4m3)
                    0, 0x7f7f7f7f,        // scale_a: every byte = 2^0
                    0, 0x7f7f7f7f);       // scale_b
    };

    stage(0, lA0, lB0);
    __syncthreads();                       // one-time full drain: tile 0 ready

    #pragma unroll
    for (int tt = 0; tt < 4; ++tt) {       // even/odd pairs, compile-time buffers
        // even step: compute ping, prefetch into pong
        stage(tt * 2 + 1, lA1, lB1);       // issue-early: 6 loads in flight
        compute(lA0, lB0);                 // ds_read+MFMA hides the load latency
        __syncthreads();                   // vmcnt(0) drain now nearly free
        // odd step: compute pong, prefetch into ping
        if (tt < 3) stage(tt * 2 + 2, lA0, lB0);
        compute(lA1, lB1);
        __syncthreads();
    }

    // epilogue: exp(10*d) = exp2(d*10/ln2); near-diag pos blocks skip rr==cc
    const float LOG2E10 = 14.4269504088896341f;
    float part = 0.f;
    if (pos && (bx >> 1) == by) {
        #pragma unroll
        for (int mi = 0; mi < 4; ++mi)
            #pragma unroll
            for (int ni = 0; ni < 2; ++ni)
                #pragma unroll
                for (int r = 0; r < 16; ++r) {
                    // C/D 32x32: col=lane&31, row=(r&3)+8*(r>>2)+4*(lane>>5)
                    int rr = m0 + wm + mi * 32 + ((r & 3) + 8 * (r >> 2) + 4 * q_);
                    int cc = n0 + wn + ni * 32 + r_;
                    if (rr != cc) part += exp2f(accf[mi][ni][r] * LOG2E10);
                }
    } else {
        #pragma unroll
        for (int mi = 0; mi < 4; ++mi)
            #pragma unroll
            for (int ni = 0; ni < 2; ++ni)
                #pragma unroll
                for (int r = 0; r < 16; ++r)
                    part += exp2f(accf[mi][ni][r] * LOG2E10);
    }

    #pragma unroll
    for (int off = 32; off >= 1; off >>= 1) part += __shfl_xor(part, off, 64);
    if (lane == 0) red[wave] = part;
    __syncthreads();
    if (tid == 0) {
        double s = (double)red[0] + (double)red[1] + (double)red[2] + (double)red[3];
        if (pos && bx >= 2 * by + 2) s *= 2.0;   // stands in for its skipped mirror
        atomicAdd(&acc[(pos ? 0 : 64) + (((unsigned)bx * 7 + (unsigned)by) & 63)], s);
        __threadfence();
        unsigned prev = __hip_atomic_fetch_add(cnt, 1u, __ATOMIC_ACQ_REL,
                                               __HIP_MEMORY_SCOPE_AGENT);
        amLast = (prev == TOTAL_BLOCKS - 1u) ? 1u : 0u;
    }
    __syncthreads();

    // fused finalize: last contributing block reduces the 128 slots.
    // slots 0..63 = pos partials (wave 0), 64..127 = neg partials (wave 1).
    if (amLast) {
        double v = 0.0;
        if (tid < 128)
            v = __hip_atomic_load(&acc[tid], __ATOMIC_ACQUIRE, __HIP_MEMORY_SCOPE_AGENT);
        #pragma unroll
        for (int off = 32; off >= 1; off >>= 1) v += __shfl_xor(v, off, 64);
        if (tid == 0)  dred[0] = v;   // pos sum
        if (tid == 64) dred[1] = v;   // neg sum
        __syncthreads();
        if (tid == 0) {
            double p = dred[0] + 8192.0 * exp(10.0);   // exact pos diagonal
            out[0] = (float)log1p(dred[1] / p);
        }
    }
}

extern "C" void kernel_launch(void* const* d_in, const int* in_sizes, int n_in,
                              void* d_out, int out_size, void* d_ws, size_t ws_size,
                              hipStream_t stream) {
    const float* zi = (const float*)d_in[0];
    const float* zj = (const float*)d_in[1];
    u8* nrm = (u8*)d_ws;                                      // [16384][512] fp8 = 8 MB
    double* acc = (double*)((char*)d_ws + (size_t)16384 * 512);
    unsigned* cnt = (unsigned*)(acc + 128);

    nrm_kernel<<<4096, 256, 0, stream>>>(zi, zj, nrm, acc, cnt);
    dim3 grid(128, 32);   // x: 16384/128 n-tiles, y: 8192/256 m-tiles
    gemm_exp_reduce<<<grid, 256, 0, stream>>>(nrm, nrm, acc, cnt, (float*)d_out);
}

// Round 3
// 149.116 us; speedup vs baseline: 1.5437x; 1.5437x over previous
//
#include <hip/hip_runtime.h>
#include <cstdint>
#include <cmath>

#define NROWS 8192
#define KDIM  512            // elements; also bytes/row in fp8

typedef int    i32x4  __attribute__((ext_vector_type(4)));
typedef int    i32x8  __attribute__((ext_vector_type(8)));
typedef float  f32x16 __attribute__((ext_vector_type(16)));
typedef unsigned char u8;

#define AS1(p) ((const __attribute__((address_space(1))) void*)(p))
#define AS3(p) ((__attribute__((address_space(3))) void*)(p))

// --- Kernel 1: row L2-normalize fp32 -> fp8 e4m3 (OCP, HW cvt), one wave/row.
// zi rows [0,8192), zj rows [8192,16384). Also zeroes the 128 accumulator slots.
__global__ __launch_bounds__(256) void nrm_kernel(const float* __restrict__ zi,
                                                  const float* __restrict__ zj,
                                                  u8* __restrict__ out,
                                                  double* __restrict__ acc) {
    if (blockIdx.x == 0 && threadIdx.x < 128) acc[threadIdx.x] = 0.0;
    const int wave = threadIdx.x >> 6;
    const int lane = threadIdx.x & 63;
    const int row  = blockIdx.x * 4 + wave;            // 0..16383
    const float* src = (row < NROWS) ? zi + (size_t)row * KDIM
                                     : zj + (size_t)(row - NROWS) * KDIM;
    float4 a = ((const float4*)src)[lane];
    float4 b = ((const float4*)src)[lane + 64];
    float ss = a.x*a.x + a.y*a.y + a.z*a.z + a.w*a.w
             + b.x*b.x + b.y*b.y + b.z*b.z + b.w*b.w;
    #pragma unroll
    for (int off = 32; off >= 1; off >>= 1) ss += __shfl_xor(ss, off, 64);
    const float inv = 1.0f / fmaxf(sqrtf(ss), 1e-12f);
    int p0 = 0, p1 = 0;
    p0 = __builtin_amdgcn_cvt_pk_fp8_f32(a.x * inv, a.y * inv, p0, false);
    p0 = __builtin_amdgcn_cvt_pk_fp8_f32(a.z * inv, a.w * inv, p0, true);
    p1 = __builtin_amdgcn_cvt_pk_fp8_f32(b.x * inv, b.y * inv, p1, false);
    p1 = __builtin_amdgcn_cvt_pk_fp8_f32(b.z * inv, b.w * inv, p1, true);
    int* dst = (int*)(out + (size_t)row * KDIM);
    dst[lane]      = p0;
    dst[lane + 64] = p1;
}

// --- Kernel 2: fused MX-fp8 A*B^T -> exp(10*dot) -> global sum.
// R14: R13's compiler-cooperative 2-phase double-buffer loop, MINUS the fused
// finalize. R12/R13 post-mortem (identical 170 us despite totally different
// inner-loop mechanics): the regression was NOT scheduling — it was the fused
// finalize's per-block cache maintenance. __threadfence() (buffer_wbl2 sc1) +
// agent-scope ACQ_REL atomic (acquire -> buffer_inv sc1 = FULL L2 INVALIDATE)
// ran at the end of all 3104 blocks (~one L2 inv per 0.2 us per XCD), evicting
// the L2-resident 8 MB operand set -> every staging load paid L3 latency.
// Evidence: FETCH_SIZE unchanged (L3 absorbed it, no HBM delta), WRITE_SIZE
// doubled 97->194 KB (wbl2 writebacks), dur exactly 2x, MfmaUtil exactly 1/2.
// Fix: separate 1-block finalize kernel (launch ~2 us << 87 us of L2 poison),
// plain RELAXED atomicAdd for partials (R11-proven; kernel boundary = visibility).
// Loop structure (T3 minimum recipe, now fairly tested with warm L2):
//   * distinct named lA0/lA1, lB0/lB1 -> compile-time buffer choice -> alias
//     analysis keeps ds_reads free of forced vmcnt(0) drains.
//   * stage-early / drain-late: issue tile t+1's 6 global_load_lds at top of
//     step, ds_read+8 MFMAs on tile t, then __syncthreads() whose vmcnt(0)
//     waits on loads that already had the compute phase to land.
// LDS XOR-swizzle unchanged (verified R2-R13, absmax 0): region = 32 rows x
// 64 B; chunk (r,b) at p = r*4 + (b ^ ((r>>1)&3)); staging inverse
// b = (lane&3)^((lane>>3)&3). Triangle skip unchanged.
__global__ __launch_bounds__(256, 2) void gemm_exp_reduce(const u8* __restrict__ A,
                                                          const u8* __restrict__ B,
                                                          double* __restrict__ acc) {
    const int bx = blockIdx.x, by = blockIdx.y;
    const bool pos = (bx < 64);
    if (pos && bx < 2 * by) return;   // strict lower-tri pos block: mirror elsewhere

    __shared__ u8 lA0[256 * 64];     // ping buffer, 16 KB (8 regions of 32r x 64B)
    __shared__ u8 lA1[256 * 64];     // pong buffer
    __shared__ u8 lB0[128 * 64];     // ping, 8 KB (4 regions)
    __shared__ u8 lB1[128 * 64];     // pong
    __shared__ float red[4];

    const int tid  = threadIdx.x;
    const int lane = tid & 63;
    const int wave = tid >> 6;
    const int m0   = by * 256;
    const int n0   = bx * 128;
    const int wm   = (wave >> 1) * 128;
    const int wn   = (wave & 1) * 64;

    f32x16 accf[4][2];
    #pragma unroll
    for (int i = 0; i < 4; ++i)
        #pragma unroll
        for (int j = 0; j < 2; ++j)
            #pragma unroll
            for (int r = 0; r < 16; ++r)
                accf[i][j][r] = 0.f;

    // staging (layout verified R2-R13): 16-row chunks of 1024 B per k-step.
    // A: wave does chunks wave*4..+3; B: wave*2..+1.
    // lane: global row = chunk*16 + (lane>>2), 16B-col bsw = (lane&3)^((lane>>3)&3).
    const int bsw = (lane & 3) ^ ((lane >> 3) & 3);
    const u8* gA0 = A + (size_t)(m0 + wave * 64 + (lane >> 2)) * KDIM + bsw * 16;
    const u8* gB0 = B + (size_t)(n0 + wave * 32 + (lane >> 2)) * KDIM + bsw * 16;
    const int ldsA = wave * 4096 + lane * 16;
    const int ldsB = wave * 2048 + lane * 16;

    // stage one BK=64 k-slice (6 x global_load_lds dwordx4 per thread)
    auto stage = [&](int t, u8 (&dA)[256 * 64], u8 (&dB)[128 * 64]) {
        const size_t kb = (size_t)t * 64;
        #pragma unroll
        for (int c = 0; c < 4; ++c)
            __builtin_amdgcn_global_load_lds(AS1(gA0 + kb + (size_t)c * 16 * KDIM),
                                             AS3(&dA[ldsA + c * 1024]), 16, 0, 0);
        #pragma unroll
        for (int c = 0; c < 2; ++c)
            __builtin_amdgcn_global_load_lds(AS1(gB0 + kb + (size_t)c * 16 * KDIM),
                                             AS3(&dB[ldsB + c * 1024]), 16, 0, 0);
    };

    // fragment read: lane row r=lane&31, k-half-of-64 q=lane>>5 (chunks 2q,2q+1);
    // swizzled position p = r*4 + ((2q) ^ ((r>>1)&3)); partner chunk at ^16.
    const int r_  = lane & 31;
    const int q_  = lane >> 5;
    const int p16 = (r_ * 4 + ((2 * q_) ^ ((r_ >> 1) & 3))) * 16;
    const int aT0 = (wave >> 1) * 4;   // A regions aT0..aT0+3 (128 rows)
    const int bT0 = (wave & 1) * 2;    // B regions bT0..bT0+1 (64 rows)

    // ds_read fragments + 8 MFMAs for one staged BK=64 tile
    auto compute = [&](const u8 (&sA)[256 * 64], const u8 (&sB)[128 * 64]) {
        i32x8 af[4], bfr[2];
        #pragma unroll
        for (int mi = 0; mi < 4; ++mi) {
            const int off = (aT0 + mi) * 2048 + p16;
            *(i32x4*)&af[mi]       = *(const i32x4*)&sA[off];
            *((i32x4*)&af[mi] + 1) = *(const i32x4*)&sA[off ^ 16];
        }
        #pragma unroll
        for (int ni = 0; ni < 2; ++ni) {
            const int off = (bT0 + ni) * 2048 + p16;
            *(i32x4*)&bfr[ni]       = *(const i32x4*)&sB[off];
            *((i32x4*)&bfr[ni] + 1) = *(const i32x4*)&sB[off ^ 16];
        }
        #pragma unroll
        for (int mi = 0; mi < 4; ++mi)
            #pragma unroll
            for (int ni = 0; ni < 2; ++ni)
                accf[mi][ni] = __builtin_amdgcn_mfma_scale_f32_32x32x64_f8f6f4(
                    af[mi], bfr[ni], accf[mi][ni],
                    0, 0,                 // cbsz=fp8(e4m3), blgp=fp8(e4m3)
                    0, 0x7f7f7f7f,        // scale_a: every byte = 2^0
                    0, 0x7f7f7f7f);       // scale_b
    };

    stage(0, lA0, lB0);
    __syncthreads();                       // one-time full drain: tile 0 ready

    #pragma unroll
    for (int tt = 0; tt < 4; ++tt) {       // even/odd pairs, compile-time buffers
        // even step: compute ping, prefetch into pong
        stage(tt * 2 + 1, lA1, lB1);       // issue-early: 6 loads in flight
        compute(lA0, lB0);                 // ds_read+MFMA hides the load latency
        __syncthreads();                   // vmcnt(0) drain now nearly free
        // odd step: compute pong, prefetch into ping
        if (tt < 3) stage(tt * 2 + 2, lA0, lB0);
        compute(lA1, lB1);
        __syncthreads();
    }

    // epilogue: exp(10*d) = exp2(d*10/ln2); near-diag pos blocks skip rr==cc
    const float LOG2E10 = 14.4269504088896341f;
    float part = 0.f;
    if (pos && (bx >> 1) == by) {
        #pragma unroll
        for (int mi = 0; mi < 4; ++mi)
            #pragma unroll
            for (int ni = 0; ni < 2; ++ni)
                #pragma unroll
                for (int r = 0; r < 16; ++r) {
                    // C/D 32x32: col=lane&31, row=(r&3)+8*(r>>2)+4*(lane>>5)
                    int rr = m0 + wm + mi * 32 + ((r & 3) + 8 * (r >> 2) + 4 * q_);
                    int cc = n0 + wn + ni * 32 + r_;
                    if (rr != cc) part += exp2f(accf[mi][ni][r] * LOG2E10);
                }
    } else {
        #pragma unroll
        for (int mi = 0; mi < 4; ++mi)
            #pragma unroll
            for (int ni = 0; ni < 2; ++ni)
                #pragma unroll
                for (int r = 0; r < 16; ++r)
                    part += exp2f(accf[mi][ni][r] * LOG2E10);
    }

    #pragma unroll
    for (int off = 32; off >= 1; off >>= 1) part += __shfl_xor(part, off, 64);
    if (lane == 0) red[wave] = part;
    __syncthreads();
    if (tid == 0) {
        double s = (double)red[0] + (double)red[1] + (double)red[2] + (double)red[3];
        if (pos && bx >= 2 * by + 2) s *= 2.0;   // stands in for its skipped mirror
        atomicAdd(&acc[(pos ? 0 : 64) + (((unsigned)bx * 7 + (unsigned)by) & 63)], s);
    }
}

// --- Kernel 3: loss = log1p(neg/pos), pos += exact diagonal 8192*e^10.
// 128 threads, one global load each; LDS reduce then scalar finish.
__global__ __launch_bounds__(128) void finalize(const double* __restrict__ acc,
                                                float* __restrict__ out) {
    __shared__ double sp[128];
    const int t = threadIdx.x;
    sp[t] = acc[t];
    __syncthreads();
    if (t == 0) {
        double p = 0.0, n = 0.0;
        #pragma unroll
        for (int i = 0; i < 64; ++i) { p += sp[i]; n += sp[64 + i]; }
        p += 8192.0 * exp(10.0);
        out[0] = (float)log1p(n / p);
    }
}

extern "C" void kernel_launch(void* const* d_in, const int* in_sizes, int n_in,
                              void* d_out, int out_size, void* d_ws, size_t ws_size,
                              hipStream_t stream) {
    const float* zi = (const float*)d_in[0];
    const float* zj = (const float*)d_in[1];
    u8* nrm = (u8*)d_ws;                                      // [16384][512] fp8 = 8 MB
    double* acc = (double*)((char*)d_ws + (size_t)16384 * 512);

    nrm_kernel<<<4096, 256, 0, stream>>>(zi, zj, nrm, acc);
    dim3 grid(128, 32);   // x: 16384/128 n-tiles, y: 8192/256 m-tiles
    gemm_exp_reduce<<<grid, 256, 0, stream>>>(nrm, nrm, acc);
    finalize<<<1, 128, 0, stream>>>(acc, (float*)d_out);
}

// Round 4
// 147.862 us; speedup vs baseline: 1.5568x; 1.0085x over previous
//
#include <hip/hip_runtime.h>
#include <cstdint>
#include <cmath>

#define NROWS 8192
#define KDIM  512            // elements; also bytes/row in fp8

typedef int    i32x4  __attribute__((ext_vector_type(4)));
typedef int    i32x8  __attribute__((ext_vector_type(8)));
typedef float  f32x16 __attribute__((ext_vector_type(16)));
typedef unsigned char u8;

#define AS1(p) ((const __attribute__((address_space(1))) void*)(p))
#define AS3(p) ((__attribute__((address_space(3))) void*)(p))

// --- Kernel 1: row L2-normalize fp32 -> fp8 e4m3 (OCP, HW cvt), one wave/row.
// zi rows [0,8192), zj rows [8192,16384). Also zeroes the 128 accumulator slots.
__global__ __launch_bounds__(256) void nrm_kernel(const float* __restrict__ zi,
                                                  const float* __restrict__ zj,
                                                  u8* __restrict__ out,
                                                  double* __restrict__ acc) {
    if (blockIdx.x == 0 && threadIdx.x < 128) acc[threadIdx.x] = 0.0;
    const int wave = threadIdx.x >> 6;
    const int lane = threadIdx.x & 63;
    const int row  = blockIdx.x * 4 + wave;            // 0..16383
    const float* src = (row < NROWS) ? zi + (size_t)row * KDIM
                                     : zj + (size_t)(row - NROWS) * KDIM;
    float4 a = ((const float4*)src)[lane];
    float4 b = ((const float4*)src)[lane + 64];
    float ss = a.x*a.x + a.y*a.y + a.z*a.z + a.w*a.w
             + b.x*b.x + b.y*b.y + b.z*b.z + b.w*b.w;
    #pragma unroll
    for (int off = 32; off >= 1; off >>= 1) ss += __shfl_xor(ss, off, 64);
    const float inv = 1.0f / fmaxf(sqrtf(ss), 1e-12f);
    int p0 = 0, p1 = 0;
    p0 = __builtin_amdgcn_cvt_pk_fp8_f32(a.x * inv, a.y * inv, p0, false);
    p0 = __builtin_amdgcn_cvt_pk_fp8_f32(a.z * inv, a.w * inv, p0, true);
    p1 = __builtin_amdgcn_cvt_pk_fp8_f32(b.x * inv, b.y * inv, p1, false);
    p1 = __builtin_amdgcn_cvt_pk_fp8_f32(b.z * inv, b.w * inv, p1, true);
    int* dst = (int*)(out + (size_t)row * KDIM);
    dst[lane]      = p0;
    dst[lane + 64] = p1;
}

// --- Kernel 2: fused MX-fp8 A*B^T -> exp(10*dot) -> global sum.
// R15: clean T3+T4 port (m218 counted-vmcnt). R14 post-mortem: 2-phase
// stage-early + __syncthreads drain == R11 baseline (both ~25% MfmaUtil) —
// consistent with m233: while the barrier drains vmcnt to 0 each step, the
// step time is the serial stage+wait+barrier chain no matter where loads are
// issued. Counted-vmcnt was never fairly tested (R12's was fence-poisoned).
// Structure here:
//   * THREE named LDS buffers (b0/b1/b2), stage distance 2: step t reads
//     buf[t%3], stages tile t+2 into buf[(t+2)%3] (distinct object; last read
//     at step t-1, safe after this step's barrier). Compile-time buffer names
//     keep alias analysis from inserting extra drains; the per-step vmcnt(6)
//     is exactly the wait the t-2-issued writes to the read-buffer require.
//   * ONE barrier per K-step (8 total, was 16): [vmcnt(6)][s_barrier]
//     [sched_barrier(0) — pins stage-writes below the barrier][ds_read frags
//     || stage issue][lgkmcnt(0)][sched_barrier(0), rule #18][setprio(1)
//     8 MFMAs setprio(0)]. vmcnt never reaches 0 until t=7: tile t+2's loads
//     get one full K-step (~400 cyc) to land; the top-of-step wait is ~free.
//   * T5 setprio now has a phase split to arbitrate (guide m218b).
// LDS 3x24 KB = 72 KB -> 2 blocks/CU (measured occupancy was ~2 anyway).
// LDS XOR-swizzle unchanged (verified R2-R14, absmax 0): region = 32 rows x
// 64 B; chunk (r,b) at p = r*4 + (b ^ ((r>>1)&3)); staging inverse
// b = (lane&3)^((lane>>3)&3). Triangle skip unchanged. Relaxed atomicAdd +
// separate finalize kernel (R14-proven: fused finalize's agent-scope acquire
// = per-block L2 invalidate = 2x regression; never re-fuse).
__global__ __launch_bounds__(256, 2) void gemm_exp_reduce(const u8* __restrict__ A,
                                                          const u8* __restrict__ B,
                                                          double* __restrict__ acc) {
    const int bx = blockIdx.x, by = blockIdx.y;
    const bool pos = (bx < 64);
    if (pos && bx < 2 * by) return;   // strict lower-tri pos block: mirror elsewhere

    __shared__ u8 lA0[256 * 64];     // 16 KB each (8 regions of 32r x 64B)
    __shared__ u8 lA1[256 * 64];
    __shared__ u8 lA2[256 * 64];
    __shared__ u8 lB0[128 * 64];     // 8 KB each (4 regions)
    __shared__ u8 lB1[128 * 64];
    __shared__ u8 lB2[128 * 64];
    __shared__ float red[4];

    const int tid  = threadIdx.x;
    const int lane = tid & 63;
    const int wave = tid >> 6;
    const int m0   = by * 256;
    const int n0   = bx * 128;
    const int wm   = (wave >> 1) * 128;
    const int wn   = (wave & 1) * 64;

    f32x16 accf[4][2];
    #pragma unroll
    for (int i = 0; i < 4; ++i)
        #pragma unroll
        for (int j = 0; j < 2; ++j)
            #pragma unroll
            for (int r = 0; r < 16; ++r)
                accf[i][j][r] = 0.f;

    // staging (layout verified R2-R14): 16-row chunks of 1024 B per k-step.
    // A: wave does chunks wave*4..+3; B: wave*2..+1.
    // lane: global row = chunk*16 + (lane>>2), 16B-col bsw = (lane&3)^((lane>>3)&3).
    const int bsw = (lane & 3) ^ ((lane >> 3) & 3);
    const u8* gA0 = A + (size_t)(m0 + wave * 64 + (lane >> 2)) * KDIM + bsw * 16;
    const u8* gB0 = B + (size_t)(n0 + wave * 32 + (lane >> 2)) * KDIM + bsw * 16;
    const int ldsA = wave * 4096 + lane * 16;
    const int ldsB = wave * 2048 + lane * 16;

    // stage one BK=64 k-slice (6 x global_load_lds dwordx4 per thread)
    auto stage = [&](int t, u8 (&dA)[256 * 64], u8 (&dB)[128 * 64]) {
        const size_t kb = (size_t)t * 64;
        #pragma unroll
        for (int c = 0; c < 4; ++c)
            __builtin_amdgcn_global_load_lds(AS1(gA0 + kb + (size_t)c * 16 * KDIM),
                                             AS3(&dA[ldsA + c * 1024]), 16, 0, 0);
        #pragma unroll
        for (int c = 0; c < 2; ++c)
            __builtin_amdgcn_global_load_lds(AS1(gB0 + kb + (size_t)c * 16 * KDIM),
                                             AS3(&dB[ldsB + c * 1024]), 16, 0, 0);
    };

    // fragment read: lane row r=lane&31, k-half-of-64 q=lane>>5 (chunks 2q,2q+1);
    // swizzled position p = r*4 + ((2q) ^ ((r>>1)&3)); partner chunk at ^16.
    const int r_  = lane & 31;
    const int q_  = lane >> 5;
    const int p16 = (r_ * 4 + ((2 * q_) ^ ((r_ >> 1) & 3))) * 16;
    const int aT0 = (wave >> 1) * 4;   // A regions aT0..aT0+3 (128 rows)
    const int bT0 = (wave & 1) * 2;    // B regions bT0..bT0+1 (64 rows)

    auto readfrag = [&](const u8 (&sA)[256 * 64], const u8 (&sB)[128 * 64],
                        i32x8 (&af)[4], i32x8 (&bfr)[2]) {
        #pragma unroll
        for (int mi = 0; mi < 4; ++mi) {
            const int off = (aT0 + mi) * 2048 + p16;
            *(i32x4*)&af[mi]       = *(const i32x4*)&sA[off];
            *((i32x4*)&af[mi] + 1) = *(const i32x4*)&sA[off ^ 16];
        }
        #pragma unroll
        for (int ni = 0; ni < 2; ++ni) {
            const int off = (bT0 + ni) * 2048 + p16;
            *(i32x4*)&bfr[ni]       = *(const i32x4*)&sB[off];
            *((i32x4*)&bfr[ni] + 1) = *(const i32x4*)&sB[off ^ 16];
        }
    };

    auto domfma = [&](const i32x8 (&af)[4], const i32x8 (&bfr)[2]) {
        #pragma unroll
        for (int mi = 0; mi < 4; ++mi)
            #pragma unroll
            for (int ni = 0; ni < 2; ++ni)
                accf[mi][ni] = __builtin_amdgcn_mfma_scale_f32_32x32x64_f8f6f4(
                    af[mi], bfr[ni], accf[mi][ni],
                    0, 0,                 // cbsz=fp8(e4m3), blgp=fp8(e4m3)
                    0, 0x7f7f7f7f,        // scale_a: every byte = 2^0
                    0, 0x7f7f7f7f);       // scale_b
    };

    stage(0, lA0, lB0);                // 6 loads in flight
    stage(1, lA1, lB1);                // 12 in flight

    // Per step: vmcnt(6) = tile t landed (t+1 stays in flight ACROSS the
    // barrier), barrier, pin, reads || stage(t+2), lgkm drain, pin, MFMAs.
#define GSTEP(RA, RB, TS, SA, SB, VM)                                  \
    {                                                                  \
        asm volatile("s_waitcnt vmcnt(" #VM ")" ::: "memory");         \
        __builtin_amdgcn_s_barrier();                                  \
        __builtin_amdgcn_sched_barrier(0);                             \
        i32x8 af[4]; i32x8 bfr[2];                                     \
        readfrag(RA, RB, af, bfr);                                     \
        if ((TS) >= 0) stage((TS), SA, SB);                            \
        asm volatile("s_waitcnt lgkmcnt(0)" ::: "memory");             \
        __builtin_amdgcn_sched_barrier(0);                             \
        __builtin_amdgcn_s_setprio(1);                                 \
        domfma(af, bfr);                                               \
        __builtin_amdgcn_s_setprio(0);                                 \
    }

    GSTEP(lA0, lB0,  2, lA2, lB2, 6)   // t=0: read tile0, stage tile2
    GSTEP(lA1, lB1,  3, lA0, lB0, 6)   // t=1
    GSTEP(lA2, lB2,  4, lA1, lB1, 6)   // t=2
    GSTEP(lA0, lB0,  5, lA2, lB2, 6)   // t=3
    GSTEP(lA1, lB1,  6, lA0, lB0, 6)   // t=4
    GSTEP(lA2, lB2,  7, lA1, lB1, 6)   // t=5
    GSTEP(lA0, lB0, -1, lA2, lB2, 6)   // t=6: tile7 still in flight
    GSTEP(lA1, lB1, -1, lA2, lB2, 0)   // t=7: final drain
#undef GSTEP

    // epilogue: exp(10*d) = exp2(d*10/ln2); near-diag pos blocks skip rr==cc
    const float LOG2E10 = 14.4269504088896341f;
    float part = 0.f;
    if (pos && (bx >> 1) == by) {
        #pragma unroll
        for (int mi = 0; mi < 4; ++mi)
            #pragma unroll
            for (int ni = 0; ni < 2; ++ni)
                #pragma unroll
                for (int r = 0; r < 16; ++r) {
                    // C/D 32x32: col=lane&31, row=(r&3)+8*(r>>2)+4*(lane>>5)
                    int rr = m0 + wm + mi * 32 + ((r & 3) + 8 * (r >> 2) + 4 * q_);
                    int cc = n0 + wn + ni * 32 + r_;
                    if (rr != cc) part += exp2f(accf[mi][ni][r] * LOG2E10);
                }
    } else {
        #pragma unroll
        for (int mi = 0; mi < 4; ++mi)
            #pragma unroll
            for (int ni = 0; ni < 2; ++ni)
                #pragma unroll
                for (int r = 0; r < 16; ++r)
                    part += exp2f(accf[mi][ni][r] * LOG2E10);
    }

    #pragma unroll
    for (int off = 32; off >= 1; off >>= 1) part += __shfl_xor(part, off, 64);
    if (lane == 0) red[wave] = part;
    __syncthreads();
    if (tid == 0) {
        double s = (double)red[0] + (double)red[1] + (double)red[2] + (double)red[3];
        if (pos && bx >= 2 * by + 2) s *= 2.0;   // stands in for its skipped mirror
        atomicAdd(&acc[(pos ? 0 : 64) + (((unsigned)bx * 7 + (unsigned)by) & 63)], s);
    }
}

// --- Kernel 3: loss = log1p(neg/pos), pos += exact diagonal 8192*e^10.
// 128 threads, one global load each; LDS reduce then scalar finish.
__global__ __launch_bounds__(128) void finalize(const double* __restrict__ acc,
                                                float* __restrict__ out) {
    __shared__ double sp[128];
    const int t = threadIdx.x;
    sp[t] = acc[t];
    __syncthreads();
    if (t == 0) {
        double p = 0.0, n = 0.0;
        #pragma unroll
        for (int i = 0; i < 64; ++i) { p += sp[i]; n += sp[64 + i]; }
        p += 8192.0 * exp(10.0);
        out[0] = (float)log1p(n / p);
    }
}

extern "C" void kernel_launch(void* const* d_in, const int* in_sizes, int n_in,
                              void* d_out, int out_size, void* d_ws, size_t ws_size,
                              hipStream_t stream) {
    const float* zi = (const float*)d_in[0];
    const float* zj = (const float*)d_in[1];
    u8* nrm = (u8*)d_ws;                                      // [16384][512] fp8 = 8 MB
    double* acc = (double*)((char*)d_ws + (size_t)16384 * 512);

    nrm_kernel<<<4096, 256, 0, stream>>>(zi, zj, nrm, acc);
    dim3 grid(128, 32);   // x: 16384/128 n-tiles, y: 8192/256 m-tiles
    gemm_exp_reduce<<<grid, 256, 0, stream>>>(nrm, nrm, acc);
    finalize<<<1, 128, 0, stream>>>(acc, (float*)d_out);
}